// Round 1
// baseline (751.197 us; speedup 1.0000x reference)
//
#include <hip/hip_runtime.h>
#include <hip/hip_bf16.h>
#include <math.h>

#define N_NODES 100000
#define E_EDGES 1600000
#define F_IN    256
#define HD      128     // H*D
#define NHEAD   4
#define DHEAD   32
#define NEG_SLOPE 0.2f
#define CAP     64      // per-dst edge bucket capacity (P(deg>64) ~ 1e-20)

// ---------------- K1: h = features[perm] @ W  (fp32) ----------------
// 64-row x 128-col tile per block, BK=32, 256 threads, 8x4 micro-tile.
__global__ __launch_bounds__(256) void k_gemm(const float* __restrict__ X,
                                              const float* __restrict__ W,
                                              const int* __restrict__ perm,
                                              float* __restrict__ h) {
    __shared__ float Xs[32][68];   // [k][m], stride 68 keeps 16B align for b128 reads
    __shared__ float Ws[32][128];  // [k][c]
    const int tid = threadIdx.x;
    const int bm  = blockIdx.x * 64;

    float acc[8][4];
#pragma unroll
    for (int i = 0; i < 8; i++)
#pragma unroll
        for (int j = 0; j < 4; j++) acc[i][j] = 0.f;

    const int tr = tid >> 5;       // 0..7  (row group)
    const int tc = tid & 31;       // 0..31 (col group)

    // X staging indices: thread loads 2 float4 of one row
    const int xr = tid >> 2;          // 0..63
    const int xq = (tid & 3) * 2;     // float4 base {0,2,4,6}
    const long prow = perm[min(bm + xr, N_NODES - 1)];
    const float* xbase = X + prow * (long)F_IN;

    for (int k0 = 0; k0 < F_IN; k0 += 32) {
        __syncthreads();
        // stage X tile (transposed: Xs[k][m])
#pragma unroll
        for (int b = 0; b < 2; b++) {
            float4 v = *(const float4*)(xbase + k0 + (xq + b) * 4);
            int kk = (xq + b) * 4;
            Xs[kk + 0][xr] = v.x;
            Xs[kk + 1][xr] = v.y;
            Xs[kk + 2][xr] = v.z;
            Xs[kk + 3][xr] = v.w;
        }
        // stage W tile
#pragma unroll
        for (int t = 0; t < 4; t++) {
            int f4 = tid + t * 256;
            int kk = f4 >> 5;
            int c4 = (f4 & 31) << 2;
            *(float4*)(&Ws[kk][c4]) = *(const float4*)(W + (long)(k0 + kk) * HD + c4);
        }
        __syncthreads();
#pragma unroll
        for (int k = 0; k < 32; k++) {
            float4 w4 = *(const float4*)(&Ws[k][tc << 2]);
            float4 xa = *(const float4*)(&Xs[k][tr * 8]);
            float4 xb = *(const float4*)(&Xs[k][tr * 8 + 4]);
            float xv[8] = {xa.x, xa.y, xa.z, xa.w, xb.x, xb.y, xb.z, xb.w};
#pragma unroll
            for (int i = 0; i < 8; i++) {
                acc[i][0] += xv[i] * w4.x;
                acc[i][1] += xv[i] * w4.y;
                acc[i][2] += xv[i] * w4.z;
                acc[i][3] += xv[i] * w4.w;
            }
        }
    }
#pragma unroll
    for (int i = 0; i < 8; i++) {
        int row = bm + tr * 8 + i;
        if (row < N_NODES) {
            *(float4*)(h + (long)row * HD + (tc << 2)) =
                make_float4(acc[i][0], acc[i][1], acc[i][2], acc[i][3]);
        }
    }
}

// ---------------- K2: el/er per (node, head) ----------------
__global__ void k_elr(const float* __restrict__ h, const float* __restrict__ al,
                      const float* __restrict__ ar, float* __restrict__ el,
                      float* __restrict__ er) {
    int i = blockIdx.x * blockDim.x + threadIdx.x;   // i = n*4 + head
    if (i >= N_NODES * NHEAD) return;
    int head = i & 3;
    const float* hp = h + (long)i * DHEAD;           // n*128 + head*32 == i*32
    float sl = 0.f, sr = 0.f;
#pragma unroll
    for (int j = 0; j < 8; j++) {
        float4 hv = *(const float4*)(hp + j * 4);
        float4 a  = *(const float4*)(al + head * DHEAD + j * 4);
        float4 b  = *(const float4*)(ar + head * DHEAD + j * 4);
        sl += hv.x * a.x + hv.y * a.y + hv.z * a.z + hv.w * a.w;
        sr += hv.x * b.x + hv.y * b.y + hv.z * b.z + hv.w * b.w;
    }
    el[i] = sl;
    er[i] = sr;
}

// ---------------- K3: per-edge exp + denom atomics + dst bucketing ----------------
__global__ void k_edge(const int* __restrict__ src, const int* __restrict__ dst,
                       const float* __restrict__ el, const float* __restrict__ er,
                       float* __restrict__ denom, int* __restrict__ cnt,
                       int* __restrict__ eidx) {
    int e = blockIdx.x * blockDim.x + threadIdx.x;
    if (e >= E_EDGES) return;
    int s = src[e], d = dst[e];
    float4 l4 = *(const float4*)(el + (long)s * 4);
    float4 r4 = *(const float4*)(er + (long)d * 4);
    float v0 = l4.x + r4.x; v0 = v0 > 0.f ? v0 : NEG_SLOPE * v0;
    float v1 = l4.y + r4.y; v1 = v1 > 0.f ? v1 : NEG_SLOPE * v1;
    float v2 = l4.z + r4.z; v2 = v2 > 0.f ? v2 : NEG_SLOPE * v2;
    float v3 = l4.w + r4.w; v3 = v3 > 0.f ? v3 : NEG_SLOPE * v3;
    atomicAdd(denom + (long)d * 4 + 0, expf(v0));
    atomicAdd(denom + (long)d * 4 + 1, expf(v1));
    atomicAdd(denom + (long)d * 4 + 2, expf(v2));
    atomicAdd(denom + (long)d * 4 + 3, expf(v3));
    int pos = atomicAdd(cnt + d, 1);
    if (pos < CAP) eidx[(long)d * CAP + pos] = e;
}

// ---------------- K4: per-node aggregation + ELU (one wave per node) ----------------
__global__ __launch_bounds__(256) void k_aggr(const int* __restrict__ src,
        const float* __restrict__ el, const float* __restrict__ er,
        const float* __restrict__ denom, const int* __restrict__ cnt,
        const int* __restrict__ eidx, const float* __restrict__ h,
        float* __restrict__ out) {
    int wid = (int)((blockIdx.x * (long)blockDim.x + threadIdx.x) >> 6);  // node
    if (wid >= N_NODES) return;
    int lane = threadIdx.x & 63;
    int head = lane >> 4;          // 2 cols per lane -> cols 2*lane, 2*lane+1, head = lane/16
    int deg = cnt[wid];
    if (deg > CAP) deg = CAP;
    float ern = er[(long)wid * 4 + head];
    float dn  = denom[(long)wid * 4 + head];
    float inv = dn > 0.f ? 1.f / dn : 0.f;
    float ax = 0.f, ay = 0.f;
    const int* eb = eidx + (long)wid * CAP;
    for (int i = 0; i < deg; i++) {
        int e = eb[i];
        int s = src[e];
        float v = el[(long)s * 4 + head] + ern;
        v = v > 0.f ? v : NEG_SLOPE * v;
        float a = expf(v) * inv;
        float2 hv = *(const float2*)(h + (long)s * HD + lane * 2);
        ax += hv.x * a;
        ay += hv.y * a;
    }
    ax = ax > 0.f ? ax : expf(ax) - 1.f;
    ay = ay > 0.f ? ay : expf(ay) - 1.f;
    *(float2*)(out + (long)wid * HD + lane * 2) = make_float2(ax, ay);
}

// ---------------- launch ----------------
extern "C" void kernel_launch(void* const* d_in, const int* in_sizes, int n_in,
                              void* d_out, int out_size, void* d_ws, size_t ws_size,
                              hipStream_t stream) {
    const float* features = (const float*)d_in[0];
    const float* W        = (const float*)d_in[1];
    const float* attn_l   = (const float*)d_in[2];
    const float* attn_r   = (const float*)d_in[3];
    const int*   src      = (const int*)d_in[4];
    const int*   dst      = (const int*)d_in[5];
    const int*   perm     = (const int*)d_in[6];
    float* out = (float*)d_out;

    char* ws = (char*)d_ws;
    const size_t OFF_H    = 0;                       // N*128 f32 = 51,200,000 B
    const size_t OFF_EL   = 51200000;                // N*4 f32   =  1,600,000 B
    const size_t OFF_ER   = 52800000;
    const size_t OFF_DEN  = 54400000;                // N*4 f32
    const size_t OFF_CNT  = 56000000;                // N int     =    400,000 B
    const size_t OFF_EIDX = 56400000;                // N*CAP int = 25,600,000 B
    // total 82,000,000 B

    float* h     = (float*)(ws + OFF_H);
    float* el    = (float*)(ws + OFF_EL);
    float* er    = (float*)(ws + OFF_ER);
    float* denom = (float*)(ws + OFF_DEN);
    int*   cnt   = (int*)(ws + OFF_CNT);
    int*   eidx  = (int*)(ws + OFF_EIDX);

    // zero denom + cnt (adjacent: 1.6MB + 0.4MB)
    hipMemsetAsync(ws + OFF_DEN, 0, 2000000, stream);

    k_gemm<<<(N_NODES + 63) / 64, 256, 0, stream>>>(features, W, perm, h);
    k_elr<<<(N_NODES * NHEAD + 255) / 256, 256, 0, stream>>>(h, attn_l, attn_r, el, er);
    k_edge<<<(E_EDGES + 255) / 256, 256, 0, stream>>>(src, dst, el, er, denom, cnt, eidx);
    k_aggr<<<(N_NODES * 64 + 255) / 256, 256, 0, stream>>>(src, el, er, denom, cnt, eidx, h, out);
}

// Round 2
// 332.546 us; speedup vs baseline: 2.2589x; 2.2589x over previous
//
#include <hip/hip_runtime.h>
#include <hip/hip_bf16.h>
#include <math.h>

#define N_NODES 100000
#define E_EDGES 1600000
#define F_IN    256
#define HD      128     // H*D
#define NHEAD   4
#define DHEAD   32
#define NEG_SLOPE 0.2f
#define CAP     64      // per-dst edge bucket capacity (P(deg>64) ~ 1e-20); == wave size

__device__ __forceinline__ unsigned short f2bf(float x) {
    unsigned int b = __float_as_uint(x);
    b += 0x7fffu + ((b >> 16) & 1u);       // round-to-nearest-even
    return (unsigned short)(b >> 16);
}

// ---------------- K1: h = features[perm] @ W (fp32 acc) + el/er epilogue + bf16 h store ----
// 64-row x 128-col tile per block, BK=32, 256 threads, 8x4 micro-tile.
__global__ __launch_bounds__(256) void k_gemm(const float* __restrict__ X,
                                              const float* __restrict__ W,
                                              const int* __restrict__ perm,
                                              const float* __restrict__ al,  // attn_l flat [128]
                                              const float* __restrict__ ar,  // attn_r flat [128]
                                              unsigned short* __restrict__ hb, // bf16 h [N][128]
                                              float* __restrict__ el,        // [N][4]
                                              float* __restrict__ er) {      // [N][4]
    __shared__ float Xs[32][68];   // [k][m]
    __shared__ float Ws[32][128];  // [k][c]
    const int tid = threadIdx.x;
    const int bm  = blockIdx.x * 64;

    float acc[8][4];
#pragma unroll
    for (int i = 0; i < 8; i++)
#pragma unroll
        for (int j = 0; j < 4; j++) acc[i][j] = 0.f;

    const int tr = tid >> 5;       // 0..7  (row group)
    const int tc = tid & 31;       // 0..31 (col group: cols 4tc..4tc+3)

    const int xr = tid >> 2;          // 0..63
    const int xq = (tid & 3) * 2;     // float4 base {0,2,4,6}
    const long prow = perm[min(bm + xr, N_NODES - 1)];
    const float* xbase = X + prow * (long)F_IN;

    for (int k0 = 0; k0 < F_IN; k0 += 32) {
        __syncthreads();
#pragma unroll
        for (int b = 0; b < 2; b++) {
            float4 v = *(const float4*)(xbase + k0 + (xq + b) * 4);
            int kk = (xq + b) * 4;
            Xs[kk + 0][xr] = v.x;
            Xs[kk + 1][xr] = v.y;
            Xs[kk + 2][xr] = v.z;
            Xs[kk + 3][xr] = v.w;
        }
#pragma unroll
        for (int t = 0; t < 4; t++) {
            int f4 = tid + t * 256;
            int kk = f4 >> 5;
            int c4 = (f4 & 31) << 2;
            *(float4*)(&Ws[kk][c4]) = *(const float4*)(W + (long)(k0 + kk) * HD + c4);
        }
        __syncthreads();
#pragma unroll
        for (int k = 0; k < 32; k++) {
            float4 w4 = *(const float4*)(&Ws[k][tc << 2]);
            float4 xa = *(const float4*)(&Xs[k][tr * 8]);
            float4 xb = *(const float4*)(&Xs[k][tr * 8 + 4]);
            float xv[8] = {xa.x, xa.y, xa.z, xa.w, xb.x, xb.y, xb.z, xb.w};
#pragma unroll
            for (int i = 0; i < 8; i++) {
                acc[i][0] += xv[i] * w4.x;
                acc[i][1] += xv[i] * w4.y;
                acc[i][2] += xv[i] * w4.z;
                acc[i][3] += xv[i] * w4.w;
            }
        }
    }

    // epilogue: bf16 h store + fused el/er (shfl-reduce over 8 lanes per (row,head))
    float al4[4], ar4[4];
#pragma unroll
    for (int j = 0; j < 4; j++) { al4[j] = al[tc * 4 + j]; ar4[j] = ar[tc * 4 + j]; }
    const int head = tc >> 3;

#pragma unroll
    for (int i = 0; i < 8; i++) {
        int row = bm + tr * 8 + i;
        float pl = acc[i][0]*al4[0] + acc[i][1]*al4[1] + acc[i][2]*al4[2] + acc[i][3]*al4[3];
        float pr = acc[i][0]*ar4[0] + acc[i][1]*ar4[1] + acc[i][2]*ar4[2] + acc[i][3]*ar4[3];
#pragma unroll
        for (int off = 1; off < 8; off <<= 1) {
            pl += __shfl_xor(pl, off, 64);
            pr += __shfl_xor(pr, off, 64);
        }
        if (row < N_NODES) {
            ushort4 u;
            u.x = f2bf(acc[i][0]); u.y = f2bf(acc[i][1]);
            u.z = f2bf(acc[i][2]); u.w = f2bf(acc[i][3]);
            *(ushort4*)(hb + (long)row * HD + (tc << 2)) = u;
            if ((tc & 7) == 0) {
                el[(long)row * 4 + head] = pl;
                er[(long)row * 4 + head] = pr;
            }
        }
    }
}

// ---------------- K2: per-edge dst bucketing (store src node id) ----------------
__global__ void k_edge(const int* __restrict__ src, const int* __restrict__ dst,
                       int* __restrict__ cnt, int* __restrict__ bucket) {
    int e = blockIdx.x * blockDim.x + threadIdx.x;
    if (e >= E_EDGES) return;
    int s = src[e], d = dst[e];
    int pos = atomicAdd(cnt + d, 1);
    if (pos < CAP) bucket[(long)d * CAP + pos] = s;
}

// ---------------- K3: per-node aggregation, inline softmax denom, ELU ----------------
__global__ __launch_bounds__(256) void k_aggr(const float* __restrict__ el,
        const float* __restrict__ er, const int* __restrict__ cnt,
        const int* __restrict__ bucket, const unsigned short* __restrict__ hb,
        float* __restrict__ out) {
    int wid = (int)((blockIdx.x * (long)blockDim.x + threadIdx.x) >> 6);  // node
    if (wid >= N_NODES) return;
    int lane = threadIdx.x & 63;
    int head = lane >> 4;          // 2 cols per lane: cols 2*lane, 2*lane+1
    int deg = cnt[wid];
    if (deg > CAP) deg = CAP;
    float ern = er[(long)wid * 4 + head];
    // whole bucket in one coalesced load, broadcast via shfl
    int myS = (lane < deg) ? bucket[(long)wid * CAP + lane] : 0;
    float ax = 0.f, ay = 0.f, asum = 0.f;
    for (int i = 0; i < deg; i++) {
        int s = __shfl(myS, i, 64);
        float v = el[(long)s * 4 + head] + ern;
        v = v > 0.f ? v : NEG_SLOPE * v;
        float a = __expf(v);
        asum += a;
        ushort2 hv = *(const ushort2*)(hb + (long)s * HD + lane * 2);
        float hx = __uint_as_float((unsigned int)hv.x << 16);
        float hy = __uint_as_float((unsigned int)hv.y << 16);
        ax += hx * a;
        ay += hy * a;
    }
    float inv = asum > 0.f ? 1.f / asum : 0.f;
    ax *= inv; ay *= inv;
    ax = ax > 0.f ? ax : __expf(ax) - 1.f;
    ay = ay > 0.f ? ay : __expf(ay) - 1.f;
    *(float2*)(out + (long)wid * HD + lane * 2) = make_float2(ax, ay);
}

// ---------------- launch ----------------
extern "C" void kernel_launch(void* const* d_in, const int* in_sizes, int n_in,
                              void* d_out, int out_size, void* d_ws, size_t ws_size,
                              hipStream_t stream) {
    const float* features = (const float*)d_in[0];
    const float* W        = (const float*)d_in[1];
    const float* attn_l   = (const float*)d_in[2];
    const float* attn_r   = (const float*)d_in[3];
    const int*   src      = (const int*)d_in[4];
    // dst = d_in[5], perm = d_in[6]
    const int*   dst      = (const int*)d_in[5];
    const int*   perm     = (const int*)d_in[6];
    float* out = (float*)d_out;

    char* ws = (char*)d_ws;
    const size_t OFF_HB   = 0;                 // N*128 bf16 = 25,600,000 B
    const size_t OFF_EL   = 25600000;          // N*4 f32   =  1,600,000 B
    const size_t OFF_ER   = 27200000;
    const size_t OFF_CNT  = 28800000;          // N int     =    400,000 B
    const size_t OFF_BKT  = 29200000;          // N*CAP int = 25,600,000 B
    // total 54,800,000 B

    unsigned short* hb   = (unsigned short*)(ws + OFF_HB);
    float* el    = (float*)(ws + OFF_EL);
    float* er    = (float*)(ws + OFF_ER);
    int*   cnt   = (int*)(ws + OFF_CNT);
    int*   bucket= (int*)(ws + OFF_BKT);

    hipMemsetAsync(ws + OFF_CNT, 0, 400000, stream);

    k_gemm<<<(N_NODES + 63) / 64, 256, 0, stream>>>(features, W, perm, attn_l, attn_r,
                                                    hb, el, er);
    k_edge<<<(E_EDGES + 255) / 256, 256, 0, stream>>>(src, dst, cnt, bucket);
    k_aggr<<<(N_NODES * 64 + 255) / 256, 256, 0, stream>>>(el, er, cnt, bucket, hb, out);
}